// Round 8
// baseline (185.419 us; speedup 1.0000x reference)
//
#include <hip/hip_runtime.h>
#include <hip/hip_bf16.h>

typedef __bf16 bf16x8 __attribute__((ext_vector_type(8)));
typedef float f32x4 __attribute__((ext_vector_type(4)));

#define GLOBAL_AS(p) ((const __attribute__((address_space(1))) void*)(p))
#define LDS_AS(p)    ((__attribute__((address_space(3))) void*)(p))
#define BAR()        asm volatile("s_barrier" ::: "memory")

static __device__ __forceinline__ unsigned short f2bf(float f) {
    union { float f; unsigned u; } v; v.f = f;
    unsigned r = v.u + 0x7FFFu + ((v.u >> 16) & 1u);
    return (unsigned short)(r >> 16);
}

// ---------------------------------------------------------------------------
// xb2 layout: 8200 rows of 1024 bf16. Batch b: zero row at b*1025, then
// x[b,0..1023] at rows b*1025+1 .. b*1025+1024. So [x[m-1], x[m]] is 2048
// CONTIGUOUS elements starting at row (m + (m>>10)).
// ---------------------------------------------------------------------------
__global__ void prep_xb(const float* __restrict__ x, unsigned short* __restrict__ xb2) {
    const int bid = blockIdx.x;
    const int c = threadIdx.x * 4;
    if (bid < 8192) {
        const int dst = bid + (bid >> 10) + 1;
        float4 v = *reinterpret_cast<const float4*>(x + (size_t)bid * 1024 + c);
        ushort4 b = make_ushort4(f2bf(v.x), f2bf(v.y), f2bf(v.z), f2bf(v.w));
        *reinterpret_cast<ushort4*>(xb2 + (size_t)dst * 1024 + c) = b;
    } else {
        const int zr = (bid - 8192) * 1025;
        *reinterpret_cast<ushort4*>(xb2 + (size_t)zr * 1024 + c) = make_ushort4(0, 0, 0, 0);
    }
}

// ---------------------------------------------------------------------------
// Transpose kernel f32 [2048][3072] (W,D flattened) -> KT bf16 [3072][2048]
// ---------------------------------------------------------------------------
__global__ void prep_kt(const float* __restrict__ K, unsigned short* __restrict__ KT) {
    __shared__ float tile[64][65];
    const int bi = blockIdx.x;   // kd tile: 32
    const int bj = blockIdx.y;   // u  tile: 48
    const int tx = threadIdx.x & 63;
    const int ty = threadIdx.x >> 6;   // 0..3

#pragma unroll
    for (int i = 0; i < 16; ++i) {
        int r = ty * 16 + i;
        tile[r][tx] = K[(size_t)(bi * 64 + r) * 3072 + bj * 64 + tx];
    }
    __syncthreads();
#pragma unroll
    for (int i = 0; i < 16; ++i) {
        int r = ty * 16 + i;
        KT[(size_t)(bj * 64 + r) * 2048 + bi * 64 + tx] = f2bf(tile[tx][r]);
    }
}

// ---------------------------------------------------------------------------
// 8-phase 256x256 GEMM, RAW s_barrier variant (single-variable test vs r4:
// builtin barrier may carry a vmcnt(0) fence drain that kills the counted-
// vmcnt pipeline; bare "s_barrier" asm cannot). All cross-wave LDS staging
// visibility is ordered by the explicit vmcnt(6/0) BEFORE the tile-boundary
// barrier; ds_read->MFMA deps are compiler register deps.
// ---------------------------------------------------------------------------
__global__ __launch_bounds__(512, 2)
void gemm_gates(const unsigned short* __restrict__ xb2,
                const unsigned short* __restrict__ BT,
                const float* __restrict__ bias,
                _Float16* __restrict__ G) {
    __shared__ __align__(16) unsigned short As[2 * 256 * 64];
    __shared__ __align__(16) unsigned short Bs[2 * 256 * 64];

    const int tid  = threadIdx.x;
    const int lane = tid & 63;
    const int w    = tid >> 6;         // 0..7
    const int wr   = w >> 2;           // 0..1 (M)
    const int wc   = w & 3;            // 0..3 (N)
    const int l15  = lane & 15, l16 = lane >> 4, l7 = lane & 7, sr8 = lane >> 3;
    const int csw  = l7 ^ sr8;         // pre-swizzled source chunk (involution)

    // XCD-aware block swizzle (384 % 8 == 0 -> bijective)
    int bid = blockIdx.x;
    bid = (bid & 7) * 48 + (bid >> 3);
    const int bx = bid % 12, by = bid / 12;
    const int m0 = by * 256, n0 = bx * 256;

    // Staging source bases per (h,j): tile-row r0 = h*128 + j*64 + w*8 (+sr8)
    const unsigned short* aP[4];
    const unsigned short* bP[4];
#pragma unroll
    for (int hj = 0; hj < 4; ++hj) {
        const int h = hj >> 1, j = hj & 1;
        const int tr = h * 128 + j * 64 + w * 8 + sr8;
        const int m  = m0 + tr;
        aP[hj] = xb2 + (size_t)(m + (m >> 10)) * 1024 + csw * 8;  // contiguous 2048-K row
        bP[hj] = BT  + (size_t)(n0 + tr) * 2048 + csw * 8;
    }

    auto stageA = [&](int kt, int h, int buf) {
#pragma unroll
        for (int j = 0; j < 2; ++j) {
            __builtin_amdgcn_global_load_lds(GLOBAL_AS(aP[h * 2 + j] + kt * 64),
                LDS_AS(As + buf * 16384 + (h * 128 + j * 64 + w * 8) * 64), 16, 0, 0);
        }
    };
    auto stageB = [&](int kt, int h, int buf) {
#pragma unroll
        for (int j = 0; j < 2; ++j) {
            __builtin_amdgcn_global_load_lds(GLOBAL_AS(bP[h * 2 + j] + kt * 64),
                LDS_AS(Bs + buf * 16384 + (h * 128 + j * 64 + w * 8) * 64), 16, 0, 0);
        }
    };

    f32x4 acc[8][4] = {};
    bf16x8 aR[4][2], bR0[2][2], bR1[2][2];

    auto rdA = [&](int buf, int mh) {
#pragma unroll
        for (int mi = 0; mi < 4; ++mi)
#pragma unroll
            for (int ks = 0; ks < 2; ++ks) {
                const int row = mh * 128 + wr * 64 + mi * 16 + l15;
                const int p   = (ks * 4 + l16) ^ l7;
                aR[mi][ks] = *reinterpret_cast<const bf16x8*>(As + buf * 16384 + row * 64 + p * 8);
            }
    };
    auto rdB = [&](int buf, int nh, bf16x8 (&br)[2][2]) {
#pragma unroll
        for (int ni = 0; ni < 2; ++ni)
#pragma unroll
            for (int ks = 0; ks < 2; ++ks) {
                const int row = nh * 128 + wc * 32 + ni * 16 + l15;
                const int p   = (ks * 4 + l16) ^ l7;
                br[ni][ks] = *reinterpret_cast<const bf16x8*>(Bs + buf * 16384 + row * 64 + p * 8);
            }
    };

#define MFMA_Q(MB, NB, BR)                                                              \
    _Pragma("unroll")                                                                   \
    for (int mi = 0; mi < 4; ++mi)                                                      \
        _Pragma("unroll")                                                               \
        for (int ni = 0; ni < 2; ++ni)                                                  \
            _Pragma("unroll")                                                           \
            for (int ks = 0; ks < 2; ++ks)                                              \
                acc[(MB) + mi][(NB) + ni] = __builtin_amdgcn_mfma_f32_16x16x32_bf16(    \
                    aR[mi][ks], BR[ni][ks], acc[(MB) + mi][(NB) + ni], 0, 0, 0);

    // Prologue: tile0 all 4 halves + tile1 first 3 halves, drain tile0 (14->6).
    stageA(0, 0, 0); stageB(0, 0, 0); stageB(0, 1, 0); stageA(0, 1, 0);
    stageA(1, 0, 1); stageB(1, 0, 1); stageB(1, 1, 1);
    asm volatile("s_waitcnt vmcnt(6)" ::: "memory");
    BAR();

    for (int t = 0; t < 32; ++t) {
        const int buf = t & 1;
        // ---- phase a: quadrant (mh0, nh0) ----
        rdA(buf, 0); rdB(buf, 0, bR0);
        if (t < 31) stageA(t + 1, 1, buf ^ 1);
        BAR();
        __builtin_amdgcn_s_setprio(1);
        MFMA_Q(0, 0, bR0)
        __builtin_amdgcn_s_setprio(0);
        BAR();
        // ---- phase b: quadrant (mh0, nh1) ----
        rdB(buf, 1, bR1);
        if (t < 30) stageA(t + 2, 0, buf);
        BAR();
        __builtin_amdgcn_s_setprio(1);
        MFMA_Q(0, 2, bR1)
        __builtin_amdgcn_s_setprio(0);
        BAR();
        // ---- phase c: quadrant (mh1, nh1) ----
        rdA(buf, 1);
        if (t < 30) stageB(t + 2, 0, buf);
        BAR();
        __builtin_amdgcn_s_setprio(1);
        MFMA_Q(4, 2, bR1)
        __builtin_amdgcn_s_setprio(0);
        BAR();
        // ---- phase d: quadrant (mh1, nh0), tile-boundary vmcnt ----
        if (t < 30) stageB(t + 2, 1, buf);
        BAR();
        __builtin_amdgcn_s_setprio(1);
        MFMA_Q(4, 0, bR0)
        __builtin_amdgcn_s_setprio(0);
        if (t < 30) { asm volatile("s_waitcnt vmcnt(6)" ::: "memory"); }
        else        { asm volatile("s_waitcnt vmcnt(0)" ::: "memory"); }
        BAR();
    }
#undef MFMA_Q

    // Epilogue: bias + activation, store f16. Gate region uniform per block.
    const int rgn = n0 >> 10;   // 0=z(tanh), 1=f, 2=o
#pragma unroll
    for (int mi8 = 0; mi8 < 8; ++mi8) {
        const int mh = mi8 >> 2, mi = mi8 & 3;
#pragma unroll
        for (int ni4 = 0; ni4 < 4; ++ni4) {
            const int nh = ni4 >> 1, ni = ni4 & 1;
            const int col = n0 + nh * 128 + wc * 32 + ni * 16 + l15;
            const float bv = bias[col];
#pragma unroll
            for (int v = 0; v < 4; ++v) {
                const int row = m0 + mh * 128 + wr * 64 + mi * 16 + l16 * 4 + v;
                const float g = acc[mi8][ni4][v] + bv;
                float val;
                if (rgn == 0) {
                    float s = 1.0f / (1.0f + __expf(-2.0f * g));
                    val = 2.0f * s - 1.0f;                       // tanh
                } else {
                    val = 1.0f / (1.0f + __expf(-g));            // sigmoid
                }
                G[(size_t)row * 3072 + col] = (_Float16)val;
            }
        }
    }
}

// ---------------------------------------------------------------------------
// Chunked parallel scan of h_t = o_t*(f_t*h_{t-1} + (1-f_t)*z_t)  (G is f16)
// Pass 1: per-(chain,chunk) compose (A,B); chunk 7 skipped (never consumed).
// ---------------------------------------------------------------------------
__global__ void scan_pass1(const _Float16* __restrict__ G, float2* __restrict__ AB) {
    const int bid = blockIdx.x;        // 224 blocks = 8 b x 7 c x 4 ug
    const int b   = bid / 28;
    const int r   = bid % 28;
    const int c   = r >> 2;            // chunk 0..6
    const int ug  = r & 3;
    const int u   = ug * 256 + threadIdx.x;
    const _Float16* g = G + (size_t)(b * 1024 + c * 128) * 3072 + u;
    float A = 1.f, Bv = 0.f;
#pragma unroll 8
    for (int i = 0; i < 128; ++i) {
        const float zv = (float)g[(size_t)i * 3072];
        const float fv = (float)g[(size_t)i * 3072 + 1024];
        const float ov = (float)g[(size_t)i * 3072 + 2048];
        const float a  = ov * fv;
        const float bb = ov * (1.f - fv) * zv;
        A  = a * A;
        Bv = a * Bv + bb;
    }
    AB[(size_t)(b * 8 + c) * 1024 + u] = make_float2(A, Bv);
}

// 1024 blocks x 64 threads: b x 8, c x 8, ug x 16 -> all 256 CUs covered.
__global__ void scan_pass23(const _Float16* __restrict__ G, const float2* __restrict__ AB,
                            float* __restrict__ out) {
    const int bid = blockIdx.x;
    const int b   = bid >> 7;
    const int r   = bid & 127;
    const int c   = r >> 4;            // chunk 0..7 (block-uniform)
    const int ug  = r & 15;
    const int u   = ug * 64 + threadIdx.x;

    float h = 0.f;
    for (int j = 0; j < c; ++j) {      // block-uniform trip count
        float2 p = AB[(size_t)(b * 8 + j) * 1024 + u];
        h = p.x * h + p.y;
    }
    const _Float16* g = G + (size_t)(b * 1024 + c * 128) * 3072 + u;
    float* o = out + (size_t)(b * 1024 + c * 128) * 1024 + u;
#pragma unroll 8
    for (int i = 0; i < 128; ++i) {
        const float zv = (float)g[(size_t)i * 3072];
        const float fv = (float)g[(size_t)i * 3072 + 1024];
        const float ov = (float)g[(size_t)i * 3072 + 2048];
        h = ov * (fv * h + (1.f - fv) * zv);
        o[(size_t)i * 1024] = h;
    }
}

// ---------------------------------------------------------------------------
extern "C" void kernel_launch(void* const* d_in, const int* in_sizes, int n_in,
                              void* d_out, int out_size, void* d_ws, size_t ws_size,
                              hipStream_t stream) {
    const float* x    = (const float*)d_in[0];   // [8,1024,1024]
    const float* kern = (const float*)d_in[1];   // [2,1024,3072]
    const float* bias = (const float*)d_in[2];   // [3072]
    float* out = (float*)d_out;                  // [8,1024,1024]

    char* ws = (char*)d_ws;
    unsigned short* xb2 = (unsigned short*)ws;                  // 8200*1024*2 = 16,793,600 B
    unsigned short* KT  = (unsigned short*)(ws + 16793600);     // 12,582,912 B
    _Float16* G         = (_Float16*)(ws + 29376512);           // 50,331,648 B
    float2* AB          = (float2*)(ws + 79708160);             //    524,288 B

    prep_xb<<<dim3(8200), dim3(256), 0, stream>>>(x, xb2);
    prep_kt<<<dim3(32, 48), dim3(256), 0, stream>>>(kern, KT);
    gemm_gates<<<dim3(384), dim3(512), 0, stream>>>(xb2, KT, bias, G);
    scan_pass1<<<dim3(224), dim3(256), 0, stream>>>(G, AB);
    scan_pass23<<<dim3(1024), dim3(64), 0, stream>>>(G, AB, out);
}

// Round 9
// 168.159 us; speedup vs baseline: 1.1026x; 1.1026x over previous
//
#include <hip/hip_runtime.h>
#include <hip/hip_bf16.h>

typedef __bf16 bf16x8 __attribute__((ext_vector_type(8)));
typedef float f32x4 __attribute__((ext_vector_type(4)));

#define GLOBAL_AS(p) ((const __attribute__((address_space(1))) void*)(p))
#define LDS_AS(p)    ((__attribute__((address_space(3))) void*)(p))
#define BAR()        asm volatile("s_barrier" ::: "memory")

typedef __attribute__((address_space(3))) const unsigned short* lds_sp;
// Inline-asm ds_read: invisible to the compiler's memory legalizer, so it
// cannot insert a conservative vmcnt(0) (global_load_lds->LDS-read dep) per
// phase. Rule #18: consumer MFMAs must be fenced by lgkmcnt(0)+sched_barrier.
#define DSREAD(dst, ptr) asm volatile("ds_read_b128 %0, %1" : "=v"(dst) : "v"((lds_sp)(ptr)))

static __device__ __forceinline__ unsigned short f2bf(float f) {
    union { float f; unsigned u; } v; v.f = f;
    unsigned r = v.u + 0x7FFFu + ((v.u >> 16) & 1u);
    return (unsigned short)(r >> 16);
}

// ---------------------------------------------------------------------------
// xb2 layout: 8200 rows of 1024 bf16. Batch b: zero row at b*1025, then
// x[b,0..1023] at rows b*1025+1 .. b*1025+1024. So [x[m-1], x[m]] is 2048
// CONTIGUOUS elements starting at row (m + (m>>10)).
// ---------------------------------------------------------------------------
__global__ void prep_xb(const float* __restrict__ x, unsigned short* __restrict__ xb2) {
    const int bid = blockIdx.x;
    const int c = threadIdx.x * 4;
    if (bid < 8192) {
        const int dst = bid + (bid >> 10) + 1;
        float4 v = *reinterpret_cast<const float4*>(x + (size_t)bid * 1024 + c);
        ushort4 b = make_ushort4(f2bf(v.x), f2bf(v.y), f2bf(v.z), f2bf(v.w));
        *reinterpret_cast<ushort4*>(xb2 + (size_t)dst * 1024 + c) = b;
    } else {
        const int zr = (bid - 8192) * 1025;
        *reinterpret_cast<ushort4*>(xb2 + (size_t)zr * 1024 + c) = make_ushort4(0, 0, 0, 0);
    }
}

// ---------------------------------------------------------------------------
// Transpose kernel f32 [2048][3072] (W,D flattened) -> KT bf16 [3072][2048]
// ---------------------------------------------------------------------------
__global__ void prep_kt(const float* __restrict__ K, unsigned short* __restrict__ KT) {
    __shared__ float tile[64][65];
    const int bi = blockIdx.x;   // kd tile: 32
    const int bj = blockIdx.y;   // u  tile: 48
    const int tx = threadIdx.x & 63;
    const int ty = threadIdx.x >> 6;   // 0..3

#pragma unroll
    for (int i = 0; i < 16; ++i) {
        int r = ty * 16 + i;
        tile[r][tx] = K[(size_t)(bi * 64 + r) * 3072 + bj * 64 + tx];
    }
    __syncthreads();
#pragma unroll
    for (int i = 0; i < 16; ++i) {
        int r = ty * 16 + i;
        KT[(size_t)(bj * 64 + r) * 2048 + bi * 64 + tx] = f2bf(tile[tx][r]);
    }
}

// ---------------------------------------------------------------------------
// 8-phase 256x256 GEMM with INLINE-ASM ds_read (the one structural element
// the previous ports missed). Counted vmcnt(6) pipeline verified by hand-
// trace: at each tile boundary the 8 oldest loads (= all of tile t+1 into
// buf^1) are complete, 6 (= tile t+2 prefetch into buf) remain in flight.
// ---------------------------------------------------------------------------
__global__ __launch_bounds__(512, 2)
void gemm_gates(const unsigned short* __restrict__ xb2,
                const unsigned short* __restrict__ BT,
                const float* __restrict__ bias,
                _Float16* __restrict__ G) {
    __shared__ __align__(16) unsigned short As[2 * 256 * 64];
    __shared__ __align__(16) unsigned short Bs[2 * 256 * 64];

    const int tid  = threadIdx.x;
    const int lane = tid & 63;
    const int w    = tid >> 6;         // 0..7
    const int wr   = w >> 2;           // 0..1 (M)
    const int wc   = w & 3;            // 0..3 (N)
    const int l15  = lane & 15, l16 = lane >> 4, l7 = lane & 7, sr8 = lane >> 3;
    const int csw  = l7 ^ sr8;         // pre-swizzled source chunk (involution)

    // XCD-aware block swizzle (384 % 8 == 0 -> bijective)
    int bid = blockIdx.x;
    bid = (bid & 7) * 48 + (bid >> 3);
    const int bx = bid % 12, by = bid / 12;
    const int m0 = by * 256, n0 = bx * 256;

    // Staging source bases per (h,j): tile-row r0 = h*128 + j*64 + w*8 (+sr8)
    const unsigned short* aP[4];
    const unsigned short* bP[4];
#pragma unroll
    for (int hj = 0; hj < 4; ++hj) {
        const int h = hj >> 1, j = hj & 1;
        const int tr = h * 128 + j * 64 + w * 8 + sr8;
        const int m  = m0 + tr;
        aP[hj] = xb2 + (size_t)(m + (m >> 10)) * 1024 + csw * 8;  // contiguous 2048-K row
        bP[hj] = BT  + (size_t)(n0 + tr) * 2048 + csw * 8;
    }

    auto stageA = [&](int kt, int h, int buf) {
#pragma unroll
        for (int j = 0; j < 2; ++j) {
            __builtin_amdgcn_global_load_lds(GLOBAL_AS(aP[h * 2 + j] + kt * 64),
                LDS_AS(As + buf * 16384 + (h * 128 + j * 64 + w * 8) * 64), 16, 0, 0);
        }
    };
    auto stageB = [&](int kt, int h, int buf) {
#pragma unroll
        for (int j = 0; j < 2; ++j) {
            __builtin_amdgcn_global_load_lds(GLOBAL_AS(bP[h * 2 + j] + kt * 64),
                LDS_AS(Bs + buf * 16384 + (h * 128 + j * 64 + w * 8) * 64), 16, 0, 0);
        }
    };

    f32x4 acc[8][4] = {};
    bf16x8 aR[4][2], bR0[2][2], bR1[2][2];

    auto rdA = [&](int buf, int mh) {
#pragma unroll
        for (int mi = 0; mi < 4; ++mi)
#pragma unroll
            for (int ks = 0; ks < 2; ++ks) {
                const int row = mh * 128 + wr * 64 + mi * 16 + l15;
                const int p   = (ks * 4 + l16) ^ l7;
                DSREAD(aR[mi][ks], As + buf * 16384 + row * 64 + p * 8);
            }
    };
    auto rdB = [&](int buf, int nh, bf16x8 (&br)[2][2]) {
#pragma unroll
        for (int ni = 0; ni < 2; ++ni)
#pragma unroll
            for (int ks = 0; ks < 2; ++ks) {
                const int row = nh * 128 + wc * 32 + ni * 16 + l15;
                const int p   = (ks * 4 + l16) ^ l7;
                DSREAD(br[ni][ks], Bs + buf * 16384 + row * 64 + p * 8);
            }
    };

#define LGKM_FENCE()  do { asm volatile("s_waitcnt lgkmcnt(0)" ::: "memory"); \
                           __builtin_amdgcn_sched_barrier(0); } while (0)

#define MFMA_Q(MB, NB, BR)                                                              \
    _Pragma("unroll")                                                                   \
    for (int mi = 0; mi < 4; ++mi)                                                      \
        _Pragma("unroll")                                                               \
        for (int ni = 0; ni < 2; ++ni)                                                  \
            _Pragma("unroll")                                                           \
            for (int ks = 0; ks < 2; ++ks)                                              \
                acc[(MB) + mi][(NB) + ni] = __builtin_amdgcn_mfma_f32_16x16x32_bf16(    \
                    aR[mi][ks], BR[ni][ks], acc[(MB) + mi][(NB) + ni], 0, 0, 0);

    // Prologue: tile0 all 4 halves + tile1 first 3 halves, drain tile0 (14->6).
    stageA(0, 0, 0); stageB(0, 0, 0); stageB(0, 1, 0); stageA(0, 1, 0);
    stageA(1, 0, 1); stageB(1, 0, 1); stageB(1, 1, 1);
    asm volatile("s_waitcnt vmcnt(6)" ::: "memory");
    BAR();

    for (int t = 0; t < 32; ++t) {
        const int buf = t & 1;
        // ---- phase a: quadrant (mh0, nh0) ----
        rdA(buf, 0); rdB(buf, 0, bR0);
        if (t < 31) stageA(t + 1, 1, buf ^ 1);
        BAR();
        LGKM_FENCE();
        __builtin_amdgcn_s_setprio(1);
        MFMA_Q(0, 0, bR0)
        __builtin_amdgcn_s_setprio(0);
        BAR();
        // ---- phase b: quadrant (mh0, nh1) ----
        rdB(buf, 1, bR1);
        if (t < 30) stageA(t + 2, 0, buf);
        BAR();
        LGKM_FENCE();
        __builtin_amdgcn_s_setprio(1);
        MFMA_Q(0, 2, bR1)
        __builtin_amdgcn_s_setprio(0);
        BAR();
        // ---- phase c: quadrant (mh1, nh1) ----
        rdA(buf, 1);
        if (t < 30) stageB(t + 2, 0, buf);
        BAR();
        LGKM_FENCE();
        __builtin_amdgcn_s_setprio(1);
        MFMA_Q(4, 2, bR1)
        __builtin_amdgcn_s_setprio(0);
        BAR();
        // ---- phase d: quadrant (mh1, nh0), tile-boundary vmcnt ----
        // (consumes aR from phase c and bR0 from phase a: already awaited)
        if (t < 30) stageB(t + 2, 1, buf);
        BAR();
        __builtin_amdgcn_s_setprio(1);
        MFMA_Q(4, 0, bR0)
        __builtin_amdgcn_s_setprio(0);
        if (t < 30) { asm volatile("s_waitcnt vmcnt(6)" ::: "memory"); }
        else        { asm volatile("s_waitcnt vmcnt(0)" ::: "memory"); }
        BAR();
    }
#undef MFMA_Q
#undef LGKM_FENCE

    // Epilogue: bias + activation, store f16. Gate region uniform per block.
    const int rgn = n0 >> 10;   // 0=z(tanh), 1=f, 2=o
#pragma unroll
    for (int mi8 = 0; mi8 < 8; ++mi8) {
        const int mh = mi8 >> 2, mi = mi8 & 3;
#pragma unroll
        for (int ni4 = 0; ni4 < 4; ++ni4) {
            const int nh = ni4 >> 1, ni = ni4 & 1;
            const int col = n0 + nh * 128 + wc * 32 + ni * 16 + l15;
            const float bv = bias[col];
#pragma unroll
            for (int v = 0; v < 4; ++v) {
                const int row = m0 + mh * 128 + wr * 64 + mi * 16 + l16 * 4 + v;
                const float g = acc[mi8][ni4][v] + bv;
                float val;
                if (rgn == 0) {
                    float s = 1.0f / (1.0f + __expf(-2.0f * g));
                    val = 2.0f * s - 1.0f;                       // tanh
                } else {
                    val = 1.0f / (1.0f + __expf(-g));            // sigmoid
                }
                G[(size_t)row * 3072 + col] = (_Float16)val;
            }
        }
    }
}

// ---------------------------------------------------------------------------
// Chunked parallel scan of h_t = o_t*(f_t*h_{t-1} + (1-f_t)*z_t)  (G is f16)
// Pass 1: per-(chain,chunk) compose (A,B); chunk 7 skipped (never consumed).
// ---------------------------------------------------------------------------
__global__ void scan_pass1(const _Float16* __restrict__ G, float2* __restrict__ AB) {
    const int bid = blockIdx.x;        // 224 blocks = 8 b x 7 c x 4 ug
    const int b   = bid / 28;
    const int r   = bid % 28;
    const int c   = r >> 2;            // chunk 0..6
    const int ug  = r & 3;
    const int u   = ug * 256 + threadIdx.x;
    const _Float16* g = G + (size_t)(b * 1024 + c * 128) * 3072 + u;
    float A = 1.f, Bv = 0.f;
#pragma unroll 8
    for (int i = 0; i < 128; ++i) {
        const float zv = (float)g[(size_t)i * 3072];
        const float fv = (float)g[(size_t)i * 3072 + 1024];
        const float ov = (float)g[(size_t)i * 3072 + 2048];
        const float a  = ov * fv;
        const float bb = ov * (1.f - fv) * zv;
        A  = a * A;
        Bv = a * Bv + bb;
    }
    AB[(size_t)(b * 8 + c) * 1024 + u] = make_float2(A, Bv);
}

// 1024 blocks x 64 threads: b x 8, c x 8, ug x 16 -> all 256 CUs covered.
__global__ void scan_pass23(const _Float16* __restrict__ G, const float2* __restrict__ AB,
                            float* __restrict__ out) {
    const int bid = blockIdx.x;
    const int b   = bid >> 7;
    const int r   = bid & 127;
    const int c   = r >> 4;            // chunk 0..7 (block-uniform)
    const int ug  = r & 15;
    const int u   = ug * 64 + threadIdx.x;

    float h = 0.f;
    for (int j = 0; j < c; ++j) {      // block-uniform trip count
        float2 p = AB[(size_t)(b * 8 + j) * 1024 + u];
        h = p.x * h + p.y;
    }
    const _Float16* g = G + (size_t)(b * 1024 + c * 128) * 3072 + u;
    float* o = out + (size_t)(b * 1024 + c * 128) * 1024 + u;
#pragma unroll 8
    for (int i = 0; i < 128; ++i) {
        const float zv = (float)g[(size_t)i * 3072];
        const float fv = (float)g[(size_t)i * 3072 + 1024];
        const float ov = (float)g[(size_t)i * 3072 + 2048];
        h = ov * (fv * h + (1.f - fv) * zv);
        o[(size_t)i * 1024] = h;
    }
}

// ---------------------------------------------------------------------------
extern "C" void kernel_launch(void* const* d_in, const int* in_sizes, int n_in,
                              void* d_out, int out_size, void* d_ws, size_t ws_size,
                              hipStream_t stream) {
    const float* x    = (const float*)d_in[0];   // [8,1024,1024]
    const float* kern = (const float*)d_in[1];   // [2,1024,3072]
    const float* bias = (const float*)d_in[2];   // [3072]
    float* out = (float*)d_out;                  // [8,1024,1024]

    char* ws = (char*)d_ws;
    unsigned short* xb2 = (unsigned short*)ws;                  // 8200*1024*2 = 16,793,600 B
    unsigned short* KT  = (unsigned short*)(ws + 16793600);     // 12,582,912 B
    _Float16* G         = (_Float16*)(ws + 29376512);           // 50,331,648 B
    float2* AB          = (float2*)(ws + 79708160);             //    524,288 B

    prep_xb<<<dim3(8200), dim3(256), 0, stream>>>(x, xb2);
    prep_kt<<<dim3(32, 48), dim3(256), 0, stream>>>(kern, KT);
    gemm_gates<<<dim3(384), dim3(512), 0, stream>>>(xb2, KT, bias, G);
    scan_pass1<<<dim3(224), dim3(256), 0, stream>>>(G, AB);
    scan_pass23<<<dim3(1024), dim3(64), 0, stream>>>(G, AB, out);
}

// Round 10
// 151.545 us; speedup vs baseline: 1.2235x; 1.1096x over previous
//
#include <hip/hip_runtime.h>
#include <hip/hip_bf16.h>

typedef __bf16 bf16x8 __attribute__((ext_vector_type(8)));
typedef float f32x4 __attribute__((ext_vector_type(4)));

#define GLOBAL_AS(p) ((const __attribute__((address_space(1))) void*)(p))
#define LDS_AS(p)    ((__attribute__((address_space(3))) void*)(p))
#define BAR()        asm volatile("s_barrier" ::: "memory")

typedef __attribute__((address_space(3))) const unsigned short* lds_sp;
// Inline-asm ds_read: invisible to the memory legalizer -> no conservative
// per-phase vmcnt(0) drain (round-9: -19us on the 256x256 kernel).
// Rule #18: consumers must be fenced by lgkmcnt(0) + sched_barrier(0).
#define DSREAD(dst, ptr) asm volatile("ds_read_b128 %0, %1" : "=v"(dst) : "v"((lds_sp)(ptr)))

static __device__ __forceinline__ unsigned short f2bf(float f) {
    union { float f; unsigned u; } v; v.f = f;
    unsigned r = v.u + 0x7FFFu + ((v.u >> 16) & 1u);
    return (unsigned short)(r >> 16);
}

// ---------------------------------------------------------------------------
// xb2 layout: 8200 rows of 1024 bf16. Batch b: zero row at b*1025, then
// x[b,0..1023] at rows b*1025+1 .. b*1025+1024. So [x[m-1], x[m]] is 2048
// CONTIGUOUS elements starting at row (m + (m>>10)).
// ---------------------------------------------------------------------------
__global__ void prep_xb(const float* __restrict__ x, unsigned short* __restrict__ xb2) {
    const int bid = blockIdx.x;
    const int c = threadIdx.x * 4;
    if (bid < 8192) {
        const int dst = bid + (bid >> 10) + 1;
        float4 v = *reinterpret_cast<const float4*>(x + (size_t)bid * 1024 + c);
        ushort4 b = make_ushort4(f2bf(v.x), f2bf(v.y), f2bf(v.z), f2bf(v.w));
        *reinterpret_cast<ushort4*>(xb2 + (size_t)dst * 1024 + c) = b;
    } else {
        const int zr = (bid - 8192) * 1025;
        *reinterpret_cast<ushort4*>(xb2 + (size_t)zr * 1024 + c) = make_ushort4(0, 0, 0, 0);
    }
}

// ---------------------------------------------------------------------------
// Transpose kernel f32 [2048][3072] (W,D flattened) -> KT bf16 [3072][2048]
// ---------------------------------------------------------------------------
__global__ void prep_kt(const float* __restrict__ K, unsigned short* __restrict__ KT) {
    __shared__ float tile[64][65];
    const int bi = blockIdx.x;   // kd tile: 32
    const int bj = blockIdx.y;   // u  tile: 48
    const int tx = threadIdx.x & 63;
    const int ty = threadIdx.x >> 6;   // 0..3

#pragma unroll
    for (int i = 0; i < 16; ++i) {
        int r = ty * 16 + i;
        tile[r][tx] = K[(size_t)(bi * 64 + r) * 3072 + bj * 64 + tx];
    }
    __syncthreads();
#pragma unroll
    for (int i = 0; i < 16; ++i) {
        int r = ty * 16 + i;
        KT[(size_t)(bj * 64 + r) * 2048 + bi * 64 + tx] = f2bf(tile[tx][r]);
    }
}

// ---------------------------------------------------------------------------
// 128x128 GEMM, double-buffered + counted vmcnt + asm ds_read.
// Combines the proven 966-TF 128-tile geometry (2 blocks/CU, 3 exact rounds
// of 512) with the round-9-validated pipeline mechanics:
//   - LDS dbuf 64KB: tile t in buf t&1, depth-2 prefetch (t+2 issued at t).
//   - vmcnt(8) at iter top = tile t's 8 loads done, t+1's 8 in flight;
//     vmcnt(0) only at the last iter. Ledger hand-traced.
//   - asm ds_read_b128 + lgkmcnt(0) + sched_barrier(0) fence (rule #18),
//     then barrier (all waves' reads done) BEFORE stage(t+2) overwrites buf.
// ---------------------------------------------------------------------------
__global__ __launch_bounds__(256, 2)
void gemm_gates(const unsigned short* __restrict__ xb2,
                const unsigned short* __restrict__ BT,
                const float* __restrict__ bias,
                _Float16* __restrict__ G) {
    __shared__ __align__(16) unsigned short As[2 * 128 * 64];
    __shared__ __align__(16) unsigned short Bs[2 * 128 * 64];

    const int tid  = threadIdx.x;
    const int lane = tid & 63;
    const int wid  = tid >> 6;
    const int wr   = wid >> 1, wc = wid & 1;
    const int m0   = blockIdx.y * 128;
    const int n0   = blockIdx.x * 128;
    const int l15  = lane & 15, l16 = lane >> 4, l7 = lane & 7;

    f32x4 acc[4][4] = {};

    const int sr = lane >> 3;   // row within 8-row group
    const int sc = lane & 7;    // 16B chunk slot this lane writes

    // Precomputed per-load source bases (pre-swizzled chunk fixed per i).
    const unsigned short* srcA[4];
    const unsigned short* srcB[4];
#pragma unroll
    for (int i = 0; i < 4; ++i) {
        const int r  = wid * 32 + i * 8 + sr;
        const int cc = sc ^ (r & 7);
        const int m  = m0 + r;
        srcA[i] = xb2 + (size_t)(m + (m >> 10)) * 1024 + cc * 8;  // 2048 contiguous K
        srcB[i] = BT  + (size_t)(n0 + r) * 2048 + cc * 8;
    }

    auto stage = [&](int kt, int buf) {
        const int kb = kt * 64;
#pragma unroll
        for (int i = 0; i < 4; ++i) {
            const int r0 = wid * 32 + i * 8;
            __builtin_amdgcn_global_load_lds(GLOBAL_AS(srcA[i] + kb),
                LDS_AS(As + buf * 8192 + r0 * 64), 16, 0, 0);
            __builtin_amdgcn_global_load_lds(GLOBAL_AS(srcB[i] + kb),
                LDS_AS(Bs + buf * 8192 + r0 * 64), 16, 0, 0);
        }
    };

    // Prologue: tiles 0 and 1 staged; 16 loads outstanding.
    stage(0, 0);
    stage(1, 1);

    auto do_iter = [&](int t, int buf) {
        // Wait: tile t's 8 loads (oldest) complete; tile t+1's stay in flight.
        if (t < 31) { asm volatile("s_waitcnt vmcnt(8)" ::: "memory"); }
        else        { asm volatile("s_waitcnt vmcnt(0)" ::: "memory"); }
        BAR();   // all waves' tile-t staging visible

        bf16x8 af[4][2], bg[4][2];
#pragma unroll
        for (int m = 0; m < 4; ++m)
#pragma unroll
            for (int ks = 0; ks < 2; ++ks) {
                const int row = wr * 64 + m * 16 + l15;
                const int p   = (ks * 4 + l16) ^ l7;
                DSREAD(af[m][ks], As + buf * 8192 + row * 64 + p * 8);
            }
#pragma unroll
        for (int n = 0; n < 4; ++n)
#pragma unroll
            for (int ks = 0; ks < 2; ++ks) {
                const int row = wc * 64 + n * 16 + l15;
                const int p   = (ks * 4 + l16) ^ l7;
                DSREAD(bg[n][ks], Bs + buf * 8192 + row * 64 + p * 8);
            }
        asm volatile("s_waitcnt lgkmcnt(0)" ::: "memory");
        __builtin_amdgcn_sched_barrier(0);
        BAR();   // all waves done reading buf -> safe to overwrite

        if (t < 30) stage(t + 2, buf);   // issue early; consumed 2 iters later

        __builtin_amdgcn_s_setprio(1);
#pragma unroll
        for (int m = 0; m < 4; ++m)
#pragma unroll
            for (int n = 0; n < 4; ++n)
#pragma unroll
                for (int ks = 0; ks < 2; ++ks)
                    acc[m][n] = __builtin_amdgcn_mfma_f32_16x16x32_bf16(
                        af[m][ks], bg[n][ks], acc[m][n], 0, 0, 0);
        __builtin_amdgcn_s_setprio(0);
    };

    for (int tt = 0; tt < 16; ++tt) {   // unrolled by 2: compile-time buf
        do_iter(tt * 2, 0);
        do_iter(tt * 2 + 1, 1);
    }

    // Epilogue: bias + activation, store f16. Gate region uniform per block.
    const int rgn = n0 >> 10;   // 0=z(tanh), 1=f, 2=o
#pragma unroll
    for (int m = 0; m < 4; ++m) {
#pragma unroll
        for (int n = 0; n < 4; ++n) {
            const int col = n0 + wc * 64 + n * 16 + l15;
            const float bv = bias[col];
#pragma unroll
            for (int v = 0; v < 4; ++v) {
                const int row = m0 + wr * 64 + m * 16 + l16 * 4 + v;
                const float g = acc[m][n][v] + bv;
                float val;
                if (rgn == 0) {
                    float s = 1.0f / (1.0f + __expf(-2.0f * g));
                    val = 2.0f * s - 1.0f;                       // tanh
                } else {
                    val = 1.0f / (1.0f + __expf(-g));            // sigmoid
                }
                G[(size_t)row * 3072 + col] = (_Float16)val;
            }
        }
    }
}

// ---------------------------------------------------------------------------
// Chunked parallel scan of h_t = o_t*(f_t*h_{t-1} + (1-f_t)*z_t)  (G is f16)
// Pass 1: per-(chain,chunk) compose (A,B); chunk 7 skipped (never consumed).
// ---------------------------------------------------------------------------
__global__ void scan_pass1(const _Float16* __restrict__ G, float2* __restrict__ AB) {
    const int bid = blockIdx.x;        // 224 blocks = 8 b x 7 c x 4 ug
    const int b   = bid / 28;
    const int r   = bid % 28;
    const int c   = r >> 2;            // chunk 0..6
    const int ug  = r & 3;
    const int u   = ug * 256 + threadIdx.x;
    const _Float16* g = G + (size_t)(b * 1024 + c * 128) * 3072 + u;
    float A = 1.f, Bv = 0.f;
#pragma unroll 8
    for (int i = 0; i < 128; ++i) {
        const float zv = (float)g[(size_t)i * 3072];
        const float fv = (float)g[(size_t)i * 3072 + 1024];
        const float ov = (float)g[(size_t)i * 3072 + 2048];
        const float a  = ov * fv;
        const float bb = ov * (1.f - fv) * zv;
        A  = a * A;
        Bv = a * Bv + bb;
    }
    AB[(size_t)(b * 8 + c) * 1024 + u] = make_float2(A, Bv);
}

// 1024 blocks x 64 threads: b x 8, c x 8, ug x 16 -> all 256 CUs covered.
__global__ void scan_pass23(const _Float16* __restrict__ G, const float2* __restrict__ AB,
                            float* __restrict__ out) {
    const int bid = blockIdx.x;
    const int b   = bid >> 7;
    const int r   = bid & 127;
    const int c   = r >> 4;            // chunk 0..7 (block-uniform)
    const int ug  = r & 15;
    const int u   = ug * 64 + threadIdx.x;

    float h = 0.f;
    for (int j = 0; j < c; ++j) {      // block-uniform trip count
        float2 p = AB[(size_t)(b * 8 + j) * 1024 + u];
        h = p.x * h + p.y;
    }
    const _Float16* g = G + (size_t)(b * 1024 + c * 128) * 3072 + u;
    float* o = out + (size_t)(b * 1024 + c * 128) * 1024 + u;
#pragma unroll 8
    for (int i = 0; i < 128; ++i) {
        const float zv = (float)g[(size_t)i * 3072];
        const float fv = (float)g[(size_t)i * 3072 + 1024];
        const float ov = (float)g[(size_t)i * 3072 + 2048];
        h = ov * (fv * h + (1.f - fv) * zv);
        o[(size_t)i * 1024] = h;
    }
}

// ---------------------------------------------------------------------------
extern "C" void kernel_launch(void* const* d_in, const int* in_sizes, int n_in,
                              void* d_out, int out_size, void* d_ws, size_t ws_size,
                              hipStream_t stream) {
    const float* x    = (const float*)d_in[0];   // [8,1024,1024]
    const float* kern = (const float*)d_in[1];   // [2,1024,3072]
    const float* bias = (const float*)d_in[2];   // [3072]
    float* out = (float*)d_out;                  // [8,1024,1024]

    char* ws = (char*)d_ws;
    unsigned short* xb2 = (unsigned short*)ws;                  // 8200*1024*2 = 16,793,600 B
    unsigned short* KT  = (unsigned short*)(ws + 16793600);     // 12,582,912 B
    _Float16* G         = (_Float16*)(ws + 29376512);           // 50,331,648 B
    float2* AB          = (float2*)(ws + 79708160);             //    524,288 B

    prep_xb<<<dim3(8200), dim3(256), 0, stream>>>(x, xb2);
    prep_kt<<<dim3(32, 48), dim3(256), 0, stream>>>(kern, KT);
    gemm_gates<<<dim3(24, 64), dim3(256), 0, stream>>>(xb2, KT, bias, G);
    scan_pass1<<<dim3(224), dim3(256), 0, stream>>>(G, AB);
    scan_pass23<<<dim3(1024), dim3(64), 0, stream>>>(G, AB, out);
}